// Round 1
// baseline (846.861 us; speedup 1.0000x reference)
//
#include <hip/hip_runtime.h>
#include <stdint.h>

#define N_ANCH 4096
#define NCLS 8
#define CN (N_ANCH * NCLS)
#define SCORE_TH 0.5f
#define IOU_TH 0.5f
#define KSEL 11
#define MAX_DET 100

__device__ __forceinline__ float iou_f(float4 a, float areaA, float4 b, float areaB) {
    float x1 = fmaxf(a.x, b.x);
    float y1 = fmaxf(a.y, b.y);
    float x2 = fminf(a.z, b.z);
    float y2 = fminf(a.w, b.w);
    float wid = x2 - x1 + 1.0f;
    float hei = y2 - y1 + 1.0f;
    float inter = wid * hei;
    float den = areaA + areaB - inter;
    float ov = (den == 0.0f) ? 0.0f : (inter / den);
    if (wid <= 0.0f || hei <= 0.0f) ov = 0.0f;
    return ov;
}

// K1: transpose inputs to per-class SoA, precompute areas, zero surv
__global__ void k_prep(const float* __restrict__ boxes, const float* __restrict__ cls,
                       const float* __restrict__ conf,
                       float4* boxesT, float* areaT, float* scoresT, float* confT, int* surv) {
    int t = blockIdx.x * blockDim.x + threadIdx.x;
    if (t >= CN) return;
    int n = t >> 3;  // anchor
    int c = t & 7;   // class
    int p = c * N_ANCH + n;
    scoresT[p] = cls[t];
    confT[p] = conf[t];
    float4 b = reinterpret_cast<const float4*>(boxes)[t];
    boxesT[p] = b;
    areaT[p] = (b.z - b.x + 1.0f) * (b.w - b.y + 1.0f);
    surv[t] = 0;
}

// K2: per-class ordered compaction of valid anchors
__global__ void __launch_bounds__(256) k_validlist(const float* __restrict__ scoresT,
                                                   int* validList, int* mVal) {
    int c = blockIdx.x;
    int tid = threadIdx.x;
    int lane = tid & 63, w = tid >> 6;
    __shared__ int wsum[4];
    __shared__ int base;
    if (tid == 0) base = 0;
    __syncthreads();
    for (int start = 0; start < N_ANCH; start += 256) {
        int n = start + tid;
        int flag = (scoresT[c * N_ANCH + n] > SCORE_TH) ? 1 : 0;
        unsigned long long mask = __ballot(flag);
        if (lane == 0) wsum[w] = __popcll(mask);
        __syncthreads();
        int rank = __popcll(mask & ((1ull << lane) - 1ull));
        int wbase = 0;
        for (int i = 0; i < w; i++) wbase += wsum[i];
        int total = wsum[0] + wsum[1] + wsum[2] + wsum[3];
        if (flag) validList[c * N_ANCH + base + wbase + rank] = n;
        __syncthreads();
        if (tid == 0) base += total;
        __syncthreads();
    }
    if (tid == 0) mVal[c] = base;
}

// K3: rep(k) = first valid j (ascending) with IoU>0.5; mark surv[rep] when a
// non-self member with (1-ov)*conf != 0 attaches.
__global__ void __launch_bounds__(256) k_rep(const float4* __restrict__ boxesT,
                                             const float* __restrict__ areaT,
                                             const float* __restrict__ scoresT,
                                             const float* __restrict__ confT,
                                             const int* __restrict__ validList,
                                             const int* __restrict__ mVal,
                                             int* rep, int* surv) {
    int t = blockIdx.x * blockDim.x + threadIdx.x;
    if (t >= CN) return;
    int c = t >> 12;
    int k = t & (N_ANCH - 1);
    if (!(scoresT[t] > SCORE_TH)) { rep[t] = -1; return; }
    float4 bk = boxesT[t];
    float ak = areaT[t];
    float cf = confT[t];
    const int* vl = validList + (c << 12);
    int mc = mVal[c];
    int rp = k;
    for (int i = 0; i < mc; i++) {
        int j = vl[i];
        float ov = iou_f(bk, ak, boxesT[(c << 12) + j], areaT[(c << 12) + j]);
        if (ov > IOU_TH) {
            rp = j;
            if (j != k) {
                float bcv = (1.0f - ov) * cf;
                if (bcv != 0.0f) surv[(c << 12) + j] = 1;  // benign same-value race
            }
            break;  // j==k always terminates (ov==1)
        }
    }
    rep[t] = rp;
}

// K4 (single block): survivor compaction (sel, count) + top-100 scores via
// 1024-bucket histogram threshold + small selection loop.
__global__ void __launch_bounds__(256) k_select(const int* __restrict__ surv,
                                                const float* __restrict__ scoresT,
                                                int* sel, int* count_g, float* cand,
                                                float* out) {
    __shared__ int wsum[4];
    __shared__ int base;
    __shared__ int hist[1024];
    __shared__ int sfx[256];
    __shared__ int thrB;
    __shared__ int ccS;
    __shared__ float candLds[4096];
    __shared__ float redV[4];
    __shared__ int redI[4];
    __shared__ float bestVs;
    __shared__ int bestIs;
    int tid = threadIdx.x, lane = tid & 63, w = tid >> 6;
    for (int i = tid; i < 1024; i += 256) hist[i] = 0;
    if (tid == 0) { base = 0; ccS = 0; thrB = 0; }
    __syncthreads();
    // pass 1: ordered compaction + histogram
    for (int start = 0; start < CN; start += 256) {
        int p = start + tid;
        int flag = surv[p];
        unsigned long long mask = __ballot(flag != 0);
        if (lane == 0) wsum[w] = __popcll(mask);
        if (flag) {
            unsigned bits = __float_as_uint(scoresT[p]);
            int bb = (int)((bits - 0x3F000000u) >> 13);
            int b = bb < 0 ? 0 : (bb > 1023 ? 1023 : bb);
            atomicAdd(&hist[b], 1);
        }
        __syncthreads();
        int rank = __popcll(mask & ((1ull << lane) - 1ull));
        int wbase = 0;
        for (int i = 0; i < w; i++) wbase += wsum[i];
        int total = wsum[0] + wsum[1] + wsum[2] + wsum[3];
        int idx = base + wbase + rank;
        if (flag && idx < MAX_DET) sel[idx] = p;
        __syncthreads();
        if (tid == 0) base += total;
        __syncthreads();
    }
    int count = base;
    if (tid == 0) *count_g = count;
    int target = count < MAX_DET ? count : MAX_DET;
    // pass 2: find largest bucket t with suffix-count >= target
    int part = hist[4 * tid] + hist[4 * tid + 1] + hist[4 * tid + 2] + hist[4 * tid + 3];
    sfx[tid] = part;
    __syncthreads();
    if (tid == 0) {
        int run = 0;
        for (int i = 255; i >= 0; i--) { int v = sfx[i]; sfx[i] = run; run += v; }
    }
    __syncthreads();
    {
        int S = sfx[tid];
        int found = -1;
        for (int b = 4 * tid + 3; b >= 4 * tid; b--) {
            S += hist[b];
            if (found < 0 && S >= target) found = b;
        }
        if (found >= 0) atomicMax(&thrB, found);
    }
    __syncthreads();
    int t0 = thrB;
    // pass 3: gather candidates (bucket >= t0)
    for (int p = tid; p < CN; p += 256) {
        if (surv[p]) {
            unsigned bits = __float_as_uint(scoresT[p]);
            int bb = (int)((bits - 0x3F000000u) >> 13);
            int b = bb < 0 ? 0 : (bb > 1023 ? 1023 : bb);
            if (b >= t0) {
                int id = atomicAdd(&ccS, 1);
                float v = __uint_as_float(bits);
                cand[id] = v;
                if (id < 4096) candLds[id] = v;
            }
        }
    }
    __threadfence_block();
    __syncthreads();
    int cc = ccS;
    float* src = (cc <= 4096) ? (float*)candLds : cand;
    // pass 4: 100 iterations of argmax with lazy invalidation by index
    int lastIdx = -1;
    for (int j = 0; j < MAX_DET; j++) {
        float bv = -1e38f;
        int bi = -1;
        for (int i = tid; i < cc; i += 256) {
            float v = src[i];
            if (i == lastIdx) { src[i] = -1e38f; v = -1e38f; }
            if (v > bv) { bv = v; bi = i; }
        }
        for (int off = 32; off > 0; off >>= 1) {
            float o = __shfl_down(bv, off);
            int oi = __shfl_down(bi, off);
            if (o > bv) { bv = o; bi = oi; }
        }
        if (lane == 0) { redV[w] = bv; redI[w] = bi; }
        __syncthreads();
        if (tid == 0) {
            float B = redV[0]; int I = redI[0];
            for (int q = 1; q < 4; q++) if (redV[q] > B) { B = redV[q]; I = redI[q]; }
            bestVs = B; bestIs = I;
            out[j] = (j < count) ? B : -1.0f;
        }
        __syncthreads();
        lastIdx = bestIs;
    }
}

// K5: one block per output slot — gather cluster members, pick 11 smallest
// (bcv,k) keys, average poses/boxes; fill -1 past count.
__global__ void __launch_bounds__(256) k_out(const float4* __restrict__ boxesT,
                                             const float* __restrict__ areaT,
                                             const float* __restrict__ confT,
                                             const float* __restrict__ poses,
                                             const int* __restrict__ validList,
                                             const int* __restrict__ mVal,
                                             const int* __restrict__ rep,
                                             const int* __restrict__ sel,
                                             const int* __restrict__ count_g,
                                             float* out) {
    int s = blockIdx.x;
    int tid = threadIdx.x;
    int count = *count_g;
    if (s >= count) {
        if (tid == 0) { out[100 + s] = -1.0f; out[1400 + s] = -1.0f; }
        if (tid < 12) out[200 + s * 12 + tid] = -1.0f;
        if (tid >= 16 && tid < 20) out[1500 + s * 4 + (tid - 16)] = -1.0f;
        return;
    }
    int p = sel[s];
    int c = p >> 12;
    int r = p & (N_ANCH - 1);
    __shared__ unsigned long long keyArr[4096];
    __shared__ int nmS;
    __shared__ int kselS[KSEL];
    __shared__ unsigned long long bestS;
    __shared__ unsigned long long redK[4];
    if (tid == 0) nmS = 0;
    __syncthreads();
    float4 br = boxesT[(c << 12) + r];
    float ar = areaT[(c << 12) + r];
    int mc = mVal[c];
    for (int i = tid; i < mc; i += 256) {
        int k = validList[(c << 12) + i];
        if (k != r && rep[(c << 12) + k] == r) {
            float ov = iou_f(br, ar, boxesT[(c << 12) + k], areaT[(c << 12) + k]);
            float bcv = (1.0f - ov) * confT[(c << 12) + k];
            if (bcv != 0.0f) {
                int id = atomicAdd(&nmS, 1);
                keyArr[id] = ((unsigned long long)__float_as_uint(bcv) << 32) | (unsigned)k;
            }
        }
    }
    __syncthreads();
    int nm = nmS;
    int dn = nm < KSEL ? nm : KSEL;
    unsigned long long lastBest = ~0ull;
    for (int j = 0; j < dn; j++) {
        unsigned long long bk = ~0ull;
        for (int i = tid; i < nm; i += 256) {
            unsigned long long v = keyArr[i];
            if (v == lastBest) { keyArr[i] = ~0ull; v = ~0ull; }
            if (v < bk) bk = v;
        }
        for (int off = 32; off > 0; off >>= 1) {
            unsigned long long o = __shfl_down(bk, off);
            if (o < bk) bk = o;
        }
        if ((tid & 63) == 0) redK[tid >> 6] = bk;
        __syncthreads();
        if (tid == 0) {
            unsigned long long B = redK[0];
            for (int q = 1; q < 4; q++) if (redK[q] < B) B = redK[q];
            bestS = B;
            kselS[j] = (int)(B & 0xFFFFFFFFull);
        }
        __syncthreads();
        lastBest = bestS;
    }
    float fdn = (float)(dn > 0 ? dn : 1);
    if (tid < 12) {
        float ssum = 0.0f;
        for (int j = 0; j < dn; j++) {
            int k = kselS[j];
            ssum += poses[(k * 8 + c) * 12 + tid];
        }
        out[200 + s * 12 + tid] = ssum / fdn;
    } else if (tid < 16) {
        int d = tid - 12;
        float ssum = 0.0f;
        for (int j = 0; j < dn; j++) {
            int k = kselS[j];
            const float* bb = (const float*)&boxesT[(c << 12) + k];
            ssum += bb[d];
        }
        out[1500 + s * 4 + d] = ssum / fdn;
    } else if (tid == 16) {
        out[100 + s] = (float)c;
    } else if (tid == 17) {
        out[1400 + s] = (float)r;
    }
}

extern "C" void kernel_launch(void* const* d_in, const int* in_sizes, int n_in,
                              void* d_out, int out_size, void* d_ws, size_t ws_size,
                              hipStream_t stream) {
    const float* boxes = (const float*)d_in[1];
    const float* cls   = (const float*)d_in[2];
    const float* poses = (const float*)d_in[3];
    const float* conf  = (const float*)d_in[4];
    float* out = (float*)d_out;

    char* ws = (char*)d_ws;
    size_t off = 0;
    auto alloc = [&](size_t bytes) {
        void* p = ws + off;
        off += (bytes + 255) & ~(size_t)255;
        return p;
    };
    float4* boxesT  = (float4*)alloc(CN * sizeof(float4));
    float*  areaT   = (float*)alloc(CN * sizeof(float));
    float*  scoresT = (float*)alloc(CN * sizeof(float));
    float*  confT   = (float*)alloc(CN * sizeof(float));
    int*    validList = (int*)alloc(CN * sizeof(int));
    int*    mVal    = (int*)alloc(64);
    int*    rep     = (int*)alloc(CN * sizeof(int));
    int*    surv    = (int*)alloc(CN * sizeof(int));
    int*    sel     = (int*)alloc(MAX_DET * sizeof(int));
    int*    count_g = (int*)alloc(64);
    float*  cand    = (float*)alloc(CN * sizeof(float));

    k_prep<<<CN / 256, 256, 0, stream>>>(boxes, cls, conf, boxesT, areaT, scoresT, confT, surv);
    k_validlist<<<NCLS, 256, 0, stream>>>(scoresT, validList, mVal);
    k_rep<<<CN / 256, 256, 0, stream>>>(boxesT, areaT, scoresT, confT, validList, mVal, rep, surv);
    k_select<<<1, 256, 0, stream>>>(surv, scoresT, sel, count_g, cand, out);
    k_out<<<MAX_DET, 256, 0, stream>>>(boxesT, areaT, confT, poses, validList, mVal, rep, sel, count_g, out);
}

// Round 2
// 210.254 us; speedup vs baseline: 4.0278x; 4.0278x over previous
//
#include <hip/hip_runtime.h>
#include <stdint.h>

#define N_ANCH 4096
#define NCLS 8
#define CN (N_ANCH * NCLS)
#define SCORE_TH 0.5f
#define IOU_TH 0.5f
#define KSEL 11
#define MAX_DET 100
#define CAND_CAP 4096

__device__ __forceinline__ float iou_f(float4 a, float areaA, float4 b, float areaB) {
    float x1 = fmaxf(a.x, b.x);
    float y1 = fmaxf(a.y, b.y);
    float x2 = fminf(a.z, b.z);
    float y2 = fminf(a.w, b.w);
    float wid = x2 - x1 + 1.0f;
    float hei = y2 - y1 + 1.0f;
    float inter = wid * hei;
    float den = areaA + areaB - inter;
    float ov = (den == 0.0f) ? 0.0f : (inter / den);
    if (wid <= 0.0f || hei <= 0.0f) ov = 0.0f;
    return ov;
}

// K1: transpose inputs to per-class SoA, precompute areas, zero surv/hist/gcnt
__global__ void k_prep(const float* __restrict__ boxes, const float* __restrict__ cls,
                       const float* __restrict__ conf,
                       float4* boxesT, float* areaT, float* scoresT, float* confT,
                       int* surv, int* hist, int* gcnt) {
    int t = blockIdx.x * blockDim.x + threadIdx.x;
    if (t >= CN) return;
    int n = t >> 3;  // anchor
    int c = t & 7;   // class
    int p = c * N_ANCH + n;
    scoresT[p] = cls[t];
    confT[p] = conf[t];
    float4 b = reinterpret_cast<const float4*>(boxes)[t];
    boxesT[p] = b;
    areaT[p] = (b.z - b.x + 1.0f) * (b.w - b.y + 1.0f);
    surv[t] = 0;
    if (t < 1024) hist[t] = 0;
    if (t == 1024) *gcnt = 0;
}

// K2: per-class ordered compaction of valid anchors
__global__ void __launch_bounds__(256) k_validlist(const float* __restrict__ scoresT,
                                                   int* validList, int* mVal) {
    int c = blockIdx.x;
    int tid = threadIdx.x;
    int lane = tid & 63, w = tid >> 6;
    __shared__ int wsum[4];
    __shared__ int base;
    if (tid == 0) base = 0;
    __syncthreads();
    for (int start = 0; start < N_ANCH; start += 256) {
        int n = start + tid;
        int flag = (scoresT[c * N_ANCH + n] > SCORE_TH) ? 1 : 0;
        unsigned long long mask = __ballot(flag);
        if (lane == 0) wsum[w] = __popcll(mask);
        __syncthreads();
        int rank = __popcll(mask & ((1ull << lane) - 1ull));
        int wbase = 0;
        for (int i = 0; i < w; i++) wbase += wsum[i];
        int total = wsum[0] + wsum[1] + wsum[2] + wsum[3];
        if (flag) validList[c * N_ANCH + base + wbase + rank] = n;
        __syncthreads();
        if (tid == 0) base += total;
        __syncthreads();
    }
    if (tid == 0) mVal[c] = base;
}

// K3: rep scan. Block = (class, 64-rank chunk of validList). 4 waves = 4
// stride phases per rank. Candidates staged in LDS tiles of 256 ranks.
__global__ void __launch_bounds__(256) k_rep(const float4* __restrict__ boxesT,
                                             const float* __restrict__ areaT,
                                             const float* __restrict__ confT,
                                             const int* __restrict__ validList,
                                             const int* __restrict__ mVal,
                                             int* rep, int* surv) {
    int bid = blockIdx.x;
    int c = bid >> 6, chunk = bid & 63;
    int mc = mVal[c];
    if (chunk * 64 >= mc) return;
    int tid = threadIdx.x;
    int lane64 = tid & 63;
    int q = tid >> 6;                 // stride phase = wave id
    int i = chunk * 64 + lane64;      // my valid-rank
    int cbase = c << 12;
    const int* vl = validList + cbase;
    __shared__ float4 sB[256];
    __shared__ float sA[256];
    __shared__ int jmin_s[64];
    if (tid < 64) jmin_s[tid] = 0x7FFFFFFF;
    bool active = (i < mc);
    float4 bk = make_float4(0.f, 0.f, 0.f, 0.f);
    float ak = 0.0f;
    int k = -1;
    if (active) {
        k = vl[i];
        bk = boxesT[cbase + k];
        ak = areaT[cbase + k];
    }
    int maxI = min(chunk * 64 + 63, mc - 1);
    int nT = (maxI >> 8) + 1;
    bool found = false;
    int fr = 0x7FFFFFFF;
    for (int T = 0; T < nT; T++) {
        int tileBase = T << 8;
        int gidx = tileBase + tid;
        __syncthreads();  // also covers jmin_s init before use
        if (gidx < mc) {
            int vj = vl[gidx];
            sB[tid] = boxesT[cbase + vj];
            sA[tid] = areaT[cbase + vj];
        }
        __syncthreads();
        if (active && !found) {
            int hi = min(i, tileBase + 255);
            for (int r = tileBase + q; r <= hi; r += 4) {
                float ov = iou_f(bk, ak, sB[r - tileBase], sA[r - tileBase]);
                if (ov > IOU_TH) { fr = r; found = true; break; }
            }
        }
    }
    if (found) atomicMin(&jmin_s[lane64], fr);
    __syncthreads();
    if (tid < 64 && active) {
        int r1 = jmin_s[tid];   // self (rank i) guarantees r1 <= i
        int j = vl[r1];
        rep[cbase + k] = j;
        if (r1 < i) {
            float ov = iou_f(bk, ak, boxesT[cbase + j], areaT[cbase + j]);
            float bcv = (1.0f - ov) * confT[cbase + k];
            if (bcv != 0.0f) surv[cbase + j] = 1;  // benign same-value race
        }
    }
}

// K4a: per-256-chunk survivor counts + global score histogram
__global__ void __launch_bounds__(256) k_survscan(const int* __restrict__ surv,
                                                  const float* __restrict__ scoresT,
                                                  int* blockCnt, int* hist) {
    int b = blockIdx.x, tid = threadIdx.x;
    int p = b * 256 + tid;
    int flag = surv[p] != 0;
    unsigned long long mask = __ballot(flag);
    __shared__ int wcnt[4];
    if ((tid & 63) == 0) wcnt[tid >> 6] = __popcll(mask);
    if (flag) {
        unsigned bits = __float_as_uint(scoresT[p]);
        int bb = (int)((bits - 0x3F000000u) >> 13);
        int bkt = bb < 0 ? 0 : (bb > 1023 ? 1023 : bb);
        atomicAdd(&hist[bkt], 1);
    }
    __syncthreads();
    if (tid == 0) blockCnt[b] = wcnt[0] + wcnt[1] + wcnt[2] + wcnt[3];
}

// K4b: single small block — chunk prefix sums + histogram threshold bucket
__global__ void __launch_bounds__(256) k_prefix(const int* __restrict__ blockCnt,
                                                const int* __restrict__ hist,
                                                int* blockOff, int* count_g, int* t0_g) {
    int tid = threadIdx.x;
    __shared__ int sfx[256];
    __shared__ int thrB;
    __shared__ int countS;
    if (tid == 0) {
        int run = 0;
        for (int i = 0; i < 128; i++) { blockOff[i] = run; run += blockCnt[i]; }
        *count_g = run; countS = run; thrB = 0;
    }
    int part = hist[4 * tid] + hist[4 * tid + 1] + hist[4 * tid + 2] + hist[4 * tid + 3];
    sfx[tid] = part;
    __syncthreads();
    if (tid == 0) {
        int run = 0;
        for (int i = 255; i >= 0; i--) { int v = sfx[i]; sfx[i] = run; run += v; }
    }
    __syncthreads();
    int count = countS;
    int target = count < MAX_DET ? count : MAX_DET;
    int S = sfx[tid];
    int found = -1;
    for (int b = 4 * tid + 3; b >= 4 * tid; b--) {
        S += hist[b];
        if (found < 0 && S >= target) found = b;
    }
    if (found >= 0) atomicMax(&thrB, found);
    __syncthreads();
    if (tid == 0) *t0_g = thrB;
}

// K4c: ordered sel-write (first 100 survivors, flat order) + candidate gather
__global__ void __launch_bounds__(256) k_selgather(const int* __restrict__ surv,
                                                   const float* __restrict__ scoresT,
                                                   const int* __restrict__ blockOff,
                                                   const int* __restrict__ t0_g,
                                                   int* sel, float* cand, int* gcnt) {
    int b = blockIdx.x, tid = threadIdx.x;
    int lane = tid & 63, w = tid >> 6;
    int p = b * 256 + tid;
    int flag = surv[p] != 0;
    unsigned long long mask = __ballot(flag);
    __shared__ int wcnt[4];
    if (lane == 0) wcnt[w] = __popcll(mask);
    __syncthreads();
    int rank = __popcll(mask & ((1ull << lane) - 1ull));
    int wbase = 0;
    for (int i = 0; i < w; i++) wbase += wcnt[i];
    int idx = blockOff[b] + wbase + rank;
    if (flag && idx < MAX_DET) sel[idx] = p;
    if (flag) {
        unsigned bits = __float_as_uint(scoresT[p]);
        int bb = (int)((bits - 0x3F000000u) >> 13);
        int bkt = bb < 0 ? 0 : (bb > 1023 ? 1023 : bb);
        if (bkt >= *t0_g) {
            int id = atomicAdd(gcnt, 1);
            if (id < CAND_CAP) cand[id] = scoresT[p];
        }
    }
}

// K4d: single block — dynamic-size bitonic sort of candidates, write top-100
__global__ void __launch_bounds__(256) k_sort(const float* __restrict__ cand,
                                              const int* __restrict__ gcnt,
                                              const int* __restrict__ count_g,
                                              float* out) {
    __shared__ float s[CAND_CAP];
    int tid = threadIdx.x;
    int cc = *gcnt; if (cc > CAND_CAP) cc = CAND_CAP;
    int count = *count_g;
    int n = 128; while (n < cc) n <<= 1;
    for (int i = tid; i < n; i += 256) s[i] = (i < cc) ? -cand[i] : 1e38f;
    __syncthreads();
    for (int kk = 2; kk <= n; kk <<= 1) {
        for (int jj = kk >> 1; jj > 0; jj >>= 1) {
            for (int i = tid; i < n; i += 256) {
                int ixj = i ^ jj;
                if (ixj > i) {
                    float a = s[i], b2 = s[ixj];
                    bool up = ((i & kk) == 0);
                    if (up ? (a > b2) : (a < b2)) { s[i] = b2; s[ixj] = a; }
                }
            }
            __syncthreads();
        }
    }
    if (tid < MAX_DET) out[tid] = (tid < count) ? -s[tid] : -1.0f;
}

// K5: one block per output slot — gather cluster members, pick 11 smallest
// (bcv,k) keys, average poses/boxes; fill -1 past count.
__global__ void __launch_bounds__(256) k_out(const float4* __restrict__ boxesT,
                                             const float* __restrict__ areaT,
                                             const float* __restrict__ confT,
                                             const float* __restrict__ poses,
                                             const int* __restrict__ validList,
                                             const int* __restrict__ mVal,
                                             const int* __restrict__ rep,
                                             const int* __restrict__ sel,
                                             const int* __restrict__ count_g,
                                             float* out) {
    int s = blockIdx.x;
    int tid = threadIdx.x;
    int count = *count_g;
    if (s >= count) {
        if (tid == 0) { out[100 + s] = -1.0f; out[1400 + s] = -1.0f; }
        if (tid < 12) out[200 + s * 12 + tid] = -1.0f;
        if (tid >= 16 && tid < 20) out[1500 + s * 4 + (tid - 16)] = -1.0f;
        return;
    }
    int p = sel[s];
    int c = p >> 12;
    int r = p & (N_ANCH - 1);
    __shared__ unsigned long long keyArr[4096];
    __shared__ int nmS;
    __shared__ int kselS[KSEL];
    __shared__ unsigned long long bestS;
    __shared__ unsigned long long redK[4];
    if (tid == 0) nmS = 0;
    __syncthreads();
    float4 br = boxesT[(c << 12) + r];
    float ar = areaT[(c << 12) + r];
    int mc = mVal[c];
    for (int i = tid; i < mc; i += 256) {
        int k = validList[(c << 12) + i];
        if (k != r && rep[(c << 12) + k] == r) {
            float ov = iou_f(br, ar, boxesT[(c << 12) + k], areaT[(c << 12) + k]);
            float bcv = (1.0f - ov) * confT[(c << 12) + k];
            if (bcv != 0.0f) {
                int id = atomicAdd(&nmS, 1);
                keyArr[id] = ((unsigned long long)__float_as_uint(bcv) << 32) | (unsigned)k;
            }
        }
    }
    __syncthreads();
    int nm = nmS;
    int dn = nm < KSEL ? nm : KSEL;
    unsigned long long lastBest = ~0ull;
    for (int j = 0; j < dn; j++) {
        unsigned long long bk = ~0ull;
        for (int i = tid; i < nm; i += 256) {
            unsigned long long v = keyArr[i];
            if (v == lastBest) { keyArr[i] = ~0ull; v = ~0ull; }
            if (v < bk) bk = v;
        }
        for (int off = 32; off > 0; off >>= 1) {
            unsigned long long o = __shfl_down(bk, off);
            if (o < bk) bk = o;
        }
        if ((tid & 63) == 0) redK[tid >> 6] = bk;
        __syncthreads();
        if (tid == 0) {
            unsigned long long B = redK[0];
            for (int q2 = 1; q2 < 4; q2++) if (redK[q2] < B) B = redK[q2];
            bestS = B;
            kselS[j] = (int)(B & 0xFFFFFFFFull);
        }
        __syncthreads();
        lastBest = bestS;
    }
    float fdn = (float)(dn > 0 ? dn : 1);
    if (tid < 12) {
        float ssum = 0.0f;
        for (int j = 0; j < dn; j++) {
            int k = kselS[j];
            ssum += poses[(k * 8 + c) * 12 + tid];
        }
        out[200 + s * 12 + tid] = ssum / fdn;
    } else if (tid < 16) {
        int d = tid - 12;
        float ssum = 0.0f;
        for (int j = 0; j < dn; j++) {
            int k = kselS[j];
            const float* bb = (const float*)&boxesT[(c << 12) + k];
            ssum += bb[d];
        }
        out[1500 + s * 4 + d] = ssum / fdn;
    } else if (tid == 16) {
        out[100 + s] = (float)c;
    } else if (tid == 17) {
        out[1400 + s] = (float)r;
    }
}

extern "C" void kernel_launch(void* const* d_in, const int* in_sizes, int n_in,
                              void* d_out, int out_size, void* d_ws, size_t ws_size,
                              hipStream_t stream) {
    const float* boxes = (const float*)d_in[1];
    const float* cls   = (const float*)d_in[2];
    const float* poses = (const float*)d_in[3];
    const float* conf  = (const float*)d_in[4];
    float* out = (float*)d_out;

    char* ws = (char*)d_ws;
    size_t off = 0;
    auto alloc = [&](size_t bytes) {
        void* p = ws + off;
        off += (bytes + 255) & ~(size_t)255;
        return p;
    };
    float4* boxesT  = (float4*)alloc(CN * sizeof(float4));
    float*  areaT   = (float*)alloc(CN * sizeof(float));
    float*  scoresT = (float*)alloc(CN * sizeof(float));
    float*  confT   = (float*)alloc(CN * sizeof(float));
    int*    validList = (int*)alloc(CN * sizeof(int));
    int*    mVal    = (int*)alloc(64);
    int*    rep     = (int*)alloc(CN * sizeof(int));
    int*    surv    = (int*)alloc(CN * sizeof(int));
    int*    sel     = (int*)alloc(MAX_DET * sizeof(int));
    int*    count_g = (int*)alloc(64);
    float*  cand    = (float*)alloc(CAND_CAP * sizeof(float));
    int*    hist    = (int*)alloc(1024 * sizeof(int));
    int*    blockCnt = (int*)alloc(128 * sizeof(int));
    int*    blockOff = (int*)alloc(128 * sizeof(int));
    int*    t0_g    = (int*)alloc(64);
    int*    gcnt    = (int*)alloc(64);

    k_prep<<<CN / 256, 256, 0, stream>>>(boxes, cls, conf, boxesT, areaT, scoresT, confT, surv, hist, gcnt);
    k_validlist<<<NCLS, 256, 0, stream>>>(scoresT, validList, mVal);
    k_rep<<<NCLS * 64, 256, 0, stream>>>(boxesT, areaT, confT, validList, mVal, rep, surv);
    k_survscan<<<128, 256, 0, stream>>>(surv, scoresT, blockCnt, hist);
    k_prefix<<<1, 256, 0, stream>>>(blockCnt, hist, blockOff, count_g, t0_g);
    k_selgather<<<128, 256, 0, stream>>>(surv, scoresT, blockOff, t0_g, sel, cand, gcnt);
    k_sort<<<1, 256, 0, stream>>>(cand, gcnt, count_g, out);
    k_out<<<MAX_DET, 256, 0, stream>>>(boxesT, areaT, confT, poses, validList, mVal, rep, sel, count_g, out);
}

// Round 3
// 138.307 us; speedup vs baseline: 6.1230x; 1.5202x over previous
//
#include <hip/hip_runtime.h>
#include <stdint.h>

#define N_ANCH 4096
#define NCLS 8
#define CN (N_ANCH * NCLS)
#define SCORE_TH 0.5f
#define IOU_TH 0.5f
#define KSEL 11
#define MAX_DET 100
#define CAND_CAP 4096
#define TILE 128
#define TPC (N_ANCH / TILE)          // 32 i/j tiles per class (worst case)
#define NTRI (TPC * (TPC + 1) / 2)   // 528 triangular tiles per class

__device__ __forceinline__ float iou_f(float4 a, float areaA, float4 b, float areaB) {
    float x1 = fmaxf(a.x, b.x);
    float y1 = fmaxf(a.y, b.y);
    float x2 = fminf(a.z, b.z);
    float y2 = fminf(a.w, b.w);
    float wid = x2 - x1 + 1.0f;
    float hei = y2 - y1 + 1.0f;
    float inter = wid * hei;
    float den = areaA + areaB - inter;
    float ov = (den == 0.0f) ? 0.0f : (inter / den);
    if (wid <= 0.0f || hei <= 0.0f) ov = 0.0f;
    return ov;
}

// K1: transpose inputs to per-class SoA, precompute areas, zero surv/hist/gcnt/minRank
__global__ void k_prep(const float* __restrict__ boxes, const float* __restrict__ cls,
                       const float* __restrict__ conf,
                       float4* boxesT, float* areaT, float* scoresT, float* confT,
                       int* surv, int* hist, int* gcnt, int* minRank) {
    int t = blockIdx.x * blockDim.x + threadIdx.x;
    if (t >= CN) return;
    int n = t >> 3;  // anchor
    int c = t & 7;   // class
    int p = c * N_ANCH + n;
    scoresT[p] = cls[t];
    confT[p] = conf[t];
    float4 b = reinterpret_cast<const float4*>(boxes)[t];
    boxesT[p] = b;
    areaT[p] = (b.z - b.x + 1.0f) * (b.w - b.y + 1.0f);
    surv[t] = 0;
    minRank[t] = 0x7FFFFFFF;
    if (t < 1024) hist[t] = 0;
    if (t == 1024) *gcnt = 0;
}

// K2: per-class ordered compaction of valid anchors
__global__ void __launch_bounds__(256) k_validlist(const float* __restrict__ scoresT,
                                                   int* validList, int* mVal) {
    int c = blockIdx.x;
    int tid = threadIdx.x;
    int lane = tid & 63, w = tid >> 6;
    __shared__ int wsum[4];
    __shared__ int base;
    if (tid == 0) base = 0;
    __syncthreads();
    for (int start = 0; start < N_ANCH; start += 256) {
        int n = start + tid;
        int flag = (scoresT[c * N_ANCH + n] > SCORE_TH) ? 1 : 0;
        unsigned long long mask = __ballot(flag);
        if (lane == 0) wsum[w] = __popcll(mask);
        __syncthreads();
        int rank = __popcll(mask & ((1ull << lane) - 1ull));
        int wbase = 0;
        for (int i = 0; i < w; i++) wbase += wsum[i];
        int total = wsum[0] + wsum[1] + wsum[2] + wsum[3];
        if (flag) validList[c * N_ANCH + base + wbase + rank] = n;
        __syncthreads();
        if (tid == 0) base += total;
        __syncthreads();
    }
    if (tid == 0) mVal[c] = base;
}

// K3a: triangular tiled rep-matrix. Block = (class, i-tile, j-tile<=i-tile),
// 128 threads (one i-rank each), j-tile staged in LDS, no-break min scan,
// one atomicMin per thread only when a match exists (rare).
__global__ void __launch_bounds__(128) k_repmat(const float4* __restrict__ boxesT,
                                                const float* __restrict__ areaT,
                                                const int* __restrict__ validList,
                                                const int* __restrict__ mVal,
                                                int* minRank) {
    int bid = blockIdx.x;
    int c = bid / NTRI;
    int t = bid - c * NTRI;
    int ci = (int)((sqrtf(8.0f * (float)t + 1.0f) - 1.0f) * 0.5f);
    while ((ci + 1) * (ci + 2) / 2 <= t) ci++;
    while (ci * (ci + 1) / 2 > t) ci--;
    int cj = t - ci * (ci + 1) / 2;
    int mc = mVal[c];
    int ib = ci * TILE, jb = cj * TILE;
    if (ib >= mc || jb >= mc) return;
    int tid = threadIdx.x;
    int cbase = c << 12;
    const int* vl = validList + cbase;
    __shared__ float4 sB[TILE];
    __shared__ float sA[TILE];
    if (jb + tid < mc) {
        int vj = vl[jb + tid];
        sB[tid] = boxesT[cbase + vj];
        sA[tid] = areaT[cbase + vj];
    }
    __syncthreads();
    int i = ib + tid;
    if (i >= mc) return;
    int k = vl[i];
    float4 bk = boxesT[cbase + k];
    float ak = areaT[cbase + k];
    // strictly j-rank < i-rank (self handled as default in k_repfinal)
    int limit = min(TILE, mc - jb);
    if (ci == cj) limit = min(limit, i - jb);
    int lmin = 0x7FFFFFFF;
    #pragma unroll 4
    for (int r = 0; r < limit; r++) {
        float ov = iou_f(bk, ak, sB[r], sA[r]);
        if (ov > IOU_TH && r < lmin) lmin = r;
    }
    if (lmin != 0x7FFFFFFF) atomicMin(&minRank[cbase + i], jb + lmin);
}

// K3b: finalize rep + surv from minRank
__global__ void __launch_bounds__(256) k_repfinal(const float4* __restrict__ boxesT,
                                                  const float* __restrict__ areaT,
                                                  const float* __restrict__ confT,
                                                  const int* __restrict__ validList,
                                                  const int* __restrict__ mVal,
                                                  const int* __restrict__ minRank,
                                                  int* rep, int* surv) {
    int t = blockIdx.x * blockDim.x + threadIdx.x;
    if (t >= CN) return;
    int c = t >> 12;
    int i = t & (N_ANCH - 1);   // rank
    int mc = mVal[c];
    if (i >= mc) return;
    int cbase = c << 12;
    const int* vl = validList + cbase;
    int k = vl[i];
    int mr = minRank[t];
    if (mr > i) mr = i;         // self
    int j = vl[mr];
    rep[cbase + k] = j;
    if (mr < i) {
        float ov = iou_f(boxesT[cbase + k], areaT[cbase + k], boxesT[cbase + j], areaT[cbase + j]);
        float bcv = (1.0f - ov) * confT[cbase + k];
        if (bcv != 0.0f) surv[cbase + j] = 1;  // benign same-value race
    }
}

// K4a: per-256-chunk survivor counts + global score histogram
__global__ void __launch_bounds__(256) k_survscan(const int* __restrict__ surv,
                                                  const float* __restrict__ scoresT,
                                                  int* blockCnt, int* hist) {
    int b = blockIdx.x, tid = threadIdx.x;
    int p = b * 256 + tid;
    int flag = surv[p] != 0;
    unsigned long long mask = __ballot(flag);
    __shared__ int wcnt[4];
    if ((tid & 63) == 0) wcnt[tid >> 6] = __popcll(mask);
    if (flag) {
        unsigned bits = __float_as_uint(scoresT[p]);
        int bb = (int)((bits - 0x3F000000u) >> 13);
        int bkt = bb < 0 ? 0 : (bb > 1023 ? 1023 : bb);
        atomicAdd(&hist[bkt], 1);
    }
    __syncthreads();
    if (tid == 0) blockCnt[b] = wcnt[0] + wcnt[1] + wcnt[2] + wcnt[3];
}

// K4b: single small block — chunk prefix sums + histogram threshold bucket
__global__ void __launch_bounds__(256) k_prefix(const int* __restrict__ blockCnt,
                                                const int* __restrict__ hist,
                                                int* blockOff, int* count_g, int* t0_g) {
    int tid = threadIdx.x;
    __shared__ int sfx[256];
    __shared__ int thrB;
    __shared__ int countS;
    if (tid == 0) {
        int run = 0;
        for (int i = 0; i < 128; i++) { blockOff[i] = run; run += blockCnt[i]; }
        *count_g = run; countS = run; thrB = 0;
    }
    int part = hist[4 * tid] + hist[4 * tid + 1] + hist[4 * tid + 2] + hist[4 * tid + 3];
    sfx[tid] = part;
    __syncthreads();
    if (tid == 0) {
        int run = 0;
        for (int i = 255; i >= 0; i--) { int v = sfx[i]; sfx[i] = run; run += v; }
    }
    __syncthreads();
    int count = countS;
    int target = count < MAX_DET ? count : MAX_DET;
    int S = sfx[tid];
    int found = -1;
    for (int b = 4 * tid + 3; b >= 4 * tid; b--) {
        S += hist[b];
        if (found < 0 && S >= target) found = b;
    }
    if (found >= 0) atomicMax(&thrB, found);
    __syncthreads();
    if (tid == 0) *t0_g = thrB;
}

// K4c: ordered sel-write (first 100 survivors, flat order) + candidate gather
__global__ void __launch_bounds__(256) k_selgather(const int* __restrict__ surv,
                                                   const float* __restrict__ scoresT,
                                                   const int* __restrict__ blockOff,
                                                   const int* __restrict__ t0_g,
                                                   int* sel, float* cand, int* gcnt) {
    int b = blockIdx.x, tid = threadIdx.x;
    int lane = tid & 63, w = tid >> 6;
    int p = b * 256 + tid;
    int flag = surv[p] != 0;
    unsigned long long mask = __ballot(flag);
    __shared__ int wcnt[4];
    if (lane == 0) wcnt[w] = __popcll(mask);
    __syncthreads();
    int rank = __popcll(mask & ((1ull << lane) - 1ull));
    int wbase = 0;
    for (int i = 0; i < w; i++) wbase += wcnt[i];
    int idx = blockOff[b] + wbase + rank;
    if (flag && idx < MAX_DET) sel[idx] = p;
    if (flag) {
        unsigned bits = __float_as_uint(scoresT[p]);
        int bb = (int)((bits - 0x3F000000u) >> 13);
        int bkt = bb < 0 ? 0 : (bb > 1023 ? 1023 : bb);
        if (bkt >= *t0_g) {
            int id = atomicAdd(gcnt, 1);
            if (id < CAND_CAP) cand[id] = scoresT[p];
        }
    }
}

// K4d: single block — dynamic-size bitonic sort of candidates, write top-100
__global__ void __launch_bounds__(256) k_sort(const float* __restrict__ cand,
                                              const int* __restrict__ gcnt,
                                              const int* __restrict__ count_g,
                                              float* out) {
    __shared__ float s[CAND_CAP];
    int tid = threadIdx.x;
    int cc = *gcnt; if (cc > CAND_CAP) cc = CAND_CAP;
    int count = *count_g;
    int n = 128; while (n < cc) n <<= 1;
    for (int i = tid; i < n; i += 256) s[i] = (i < cc) ? -cand[i] : 1e38f;
    __syncthreads();
    for (int kk = 2; kk <= n; kk <<= 1) {
        for (int jj = kk >> 1; jj > 0; jj >>= 1) {
            for (int i = tid; i < n; i += 256) {
                int ixj = i ^ jj;
                if (ixj > i) {
                    float a = s[i], b2 = s[ixj];
                    bool up = ((i & kk) == 0);
                    if (up ? (a > b2) : (a < b2)) { s[i] = b2; s[ixj] = a; }
                }
            }
            __syncthreads();
        }
    }
    if (tid < MAX_DET) out[tid] = (tid < count) ? -s[tid] : -1.0f;
}

// K5: one block per output slot — gather cluster members, pick 11 smallest
// (bcv,k) keys, average poses/boxes; fill -1 past count.
__global__ void __launch_bounds__(256) k_out(const float4* __restrict__ boxesT,
                                             const float* __restrict__ areaT,
                                             const float* __restrict__ confT,
                                             const float* __restrict__ poses,
                                             const int* __restrict__ validList,
                                             const int* __restrict__ mVal,
                                             const int* __restrict__ rep,
                                             const int* __restrict__ sel,
                                             const int* __restrict__ count_g,
                                             float* out) {
    int s = blockIdx.x;
    int tid = threadIdx.x;
    int count = *count_g;
    if (s >= count) {
        if (tid == 0) { out[100 + s] = -1.0f; out[1400 + s] = -1.0f; }
        if (tid < 12) out[200 + s * 12 + tid] = -1.0f;
        if (tid >= 16 && tid < 20) out[1500 + s * 4 + (tid - 16)] = -1.0f;
        return;
    }
    int p = sel[s];
    int c = p >> 12;
    int r = p & (N_ANCH - 1);
    __shared__ unsigned long long keyArr[4096];
    __shared__ int nmS;
    __shared__ int kselS[KSEL];
    __shared__ unsigned long long bestS;
    __shared__ unsigned long long redK[4];
    if (tid == 0) nmS = 0;
    __syncthreads();
    float4 br = boxesT[(c << 12) + r];
    float ar = areaT[(c << 12) + r];
    int mc = mVal[c];
    for (int i = tid; i < mc; i += 256) {
        int k = validList[(c << 12) + i];
        if (k != r && rep[(c << 12) + k] == r) {
            float ov = iou_f(br, ar, boxesT[(c << 12) + k], areaT[(c << 12) + k]);
            float bcv = (1.0f - ov) * confT[(c << 12) + k];
            if (bcv != 0.0f) {
                int id = atomicAdd(&nmS, 1);
                keyArr[id] = ((unsigned long long)__float_as_uint(bcv) << 32) | (unsigned)k;
            }
        }
    }
    __syncthreads();
    int nm = nmS;
    int dn = nm < KSEL ? nm : KSEL;
    unsigned long long lastBest = ~0ull;
    for (int j = 0; j < dn; j++) {
        unsigned long long bk = ~0ull;
        for (int i = tid; i < nm; i += 256) {
            unsigned long long v = keyArr[i];
            if (v == lastBest) { keyArr[i] = ~0ull; v = ~0ull; }
            if (v < bk) bk = v;
        }
        for (int off = 32; off > 0; off >>= 1) {
            unsigned long long o = __shfl_down(bk, off);
            if (o < bk) bk = o;
        }
        if ((tid & 63) == 0) redK[tid >> 6] = bk;
        __syncthreads();
        if (tid == 0) {
            unsigned long long B = redK[0];
            for (int q2 = 1; q2 < 4; q2++) if (redK[q2] < B) B = redK[q2];
            bestS = B;
            kselS[j] = (int)(B & 0xFFFFFFFFull);
        }
        __syncthreads();
        lastBest = bestS;
    }
    float fdn = (float)(dn > 0 ? dn : 1);
    if (tid < 12) {
        float ssum = 0.0f;
        for (int j = 0; j < dn; j++) {
            int k = kselS[j];
            ssum += poses[(k * 8 + c) * 12 + tid];
        }
        out[200 + s * 12 + tid] = ssum / fdn;
    } else if (tid < 16) {
        int d = tid - 12;
        float ssum = 0.0f;
        for (int j = 0; j < dn; j++) {
            int k = kselS[j];
            const float* bb = (const float*)&boxesT[(c << 12) + k];
            ssum += bb[d];
        }
        out[1500 + s * 4 + d] = ssum / fdn;
    } else if (tid == 16) {
        out[100 + s] = (float)c;
    } else if (tid == 17) {
        out[1400 + s] = (float)r;
    }
}

extern "C" void kernel_launch(void* const* d_in, const int* in_sizes, int n_in,
                              void* d_out, int out_size, void* d_ws, size_t ws_size,
                              hipStream_t stream) {
    const float* boxes = (const float*)d_in[1];
    const float* cls   = (const float*)d_in[2];
    const float* poses = (const float*)d_in[3];
    const float* conf  = (const float*)d_in[4];
    float* out = (float*)d_out;

    char* ws = (char*)d_ws;
    size_t off = 0;
    auto alloc = [&](size_t bytes) {
        void* p = ws + off;
        off += (bytes + 255) & ~(size_t)255;
        return p;
    };
    float4* boxesT  = (float4*)alloc(CN * sizeof(float4));
    float*  areaT   = (float*)alloc(CN * sizeof(float));
    float*  scoresT = (float*)alloc(CN * sizeof(float));
    float*  confT   = (float*)alloc(CN * sizeof(float));
    int*    validList = (int*)alloc(CN * sizeof(int));
    int*    mVal    = (int*)alloc(64);
    int*    rep     = (int*)alloc(CN * sizeof(int));
    int*    surv    = (int*)alloc(CN * sizeof(int));
    int*    sel     = (int*)alloc(MAX_DET * sizeof(int));
    int*    count_g = (int*)alloc(64);
    float*  cand    = (float*)alloc(CAND_CAP * sizeof(float));
    int*    hist    = (int*)alloc(1024 * sizeof(int));
    int*    blockCnt = (int*)alloc(128 * sizeof(int));
    int*    blockOff = (int*)alloc(128 * sizeof(int));
    int*    t0_g    = (int*)alloc(64);
    int*    gcnt    = (int*)alloc(64);
    int*    minRank = (int*)alloc(CN * sizeof(int));

    k_prep<<<CN / 256, 256, 0, stream>>>(boxes, cls, conf, boxesT, areaT, scoresT, confT, surv, hist, gcnt, minRank);
    k_validlist<<<NCLS, 256, 0, stream>>>(scoresT, validList, mVal);
    k_repmat<<<NCLS * NTRI, 128, 0, stream>>>(boxesT, areaT, validList, mVal, minRank);
    k_repfinal<<<CN / 256, 256, 0, stream>>>(boxesT, areaT, confT, validList, mVal, minRank, rep, surv);
    k_survscan<<<128, 256, 0, stream>>>(surv, scoresT, blockCnt, hist);
    k_prefix<<<1, 256, 0, stream>>>(blockCnt, hist, blockOff, count_g, t0_g);
    k_selgather<<<128, 256, 0, stream>>>(surv, scoresT, blockOff, t0_g, sel, cand, gcnt);
    k_sort<<<1, 256, 0, stream>>>(cand, gcnt, count_g, out);
    k_out<<<MAX_DET, 256, 0, stream>>>(boxesT, areaT, confT, poses, validList, mVal, rep, sel, count_g, out);
}